// Round 1
// baseline (629.069 us; speedup 1.0000x reference)
//
#include <hip/hip_runtime.h>
#include <math.h>

// NeuralTPP: B=4096 sequences, L=512 steps, H=HH=32.
// Layout: 32 lanes per batch element (lane i owns hidden unit i),
// 2 batch elements per wave, 256-thread blocks = 8 batch elems/block.
// Weights register-resident (128 VGPR/lane), h broadcast via __shfl width 32.

constexpr int Bn = 4096;
constexpr int Ln = 512;
constexpr int Hn = 32;
constexpr float EPSf = 1e-8f;

__device__ __forceinline__ float sigmoidf_(float x) {
    return __fdividef(1.0f, 1.0f + __expf(-x));
}
__device__ __forceinline__ float tanhf_(float x) {
    x = fminf(x, 15.0f);                  // avoid inf/inf; |x| <= ~7 in practice
    const float e = __expf(2.0f * x);
    return __fdividef(e - 1.0f, e + 1.0f);
}
__device__ __forceinline__ float softplusf_(float x) {
    return fmaxf(x, 0.0f) + __logf(1.0f + __expf(-fabsf(x)));
}

__global__ __launch_bounds__(256)
void tpp_main(const float* __restrict__ deltas,
              const float* __restrict__ mask,
              const float* __restrict__ w_ih,
              const float* __restrict__ w_hh,
              const float* __restrict__ b_ih,
              const float* __restrict__ b_hh,
              const float* __restrict__ w1,
              const float* __restrict__ b1,
              const float* __restrict__ w2,
              const float* __restrict__ b2,
              float* __restrict__ partials)   // [2 * gridDim.x]
{
    const int tid = threadIdx.x;
    const int grp = tid >> 5;            // 0..7 within block
    const int i   = tid & 31;            // hidden-unit index
    const int b   = blockIdx.x * 8 + grp;

    // ---- preload weights into registers (rows for unit i) ----
    float whr[32], whz[32], whn[32], w1h[32];
    const float* pr = w_hh + (size_t)i * Hn;            // r-gate row i
    const float* pz = w_hh + (size_t)(Hn + i) * Hn;     // z-gate row i
    const float* pn = w_hh + (size_t)(2 * Hn + i) * Hn; // n-gate row i
    const float* p1 = w1 + (size_t)i * (Hn + 1);        // w1 row i: [tau | h...]
#pragma unroll
    for (int j = 0; j < 32; ++j) {
        whr[j] = pr[j];
        whz[j] = pz[j];
        whn[j] = pn[j];
        w1h[j] = p1[1 + j];
    }
    const float wihr = w_ih[i], wihz = w_ih[Hn + i], wihn = w_ih[2 * Hn + i];
    const float bihr = b_ih[i], bihz = b_ih[Hn + i], bihn = b_ih[2 * Hn + i];
    const float bhhr = b_hh[i], bhhz = b_hh[Hn + i], bhhn = b_hh[2 * Hn + i];
    const float w1t = p1[0];
    const float b1i = b1[i];
    const float w2i = w2[i];
    const float ci  = w1t * w2i;         // for dphi reduction
    const float b2v = b2[0];

    const float* dp = deltas + (size_t)b * Ln;
    const float* mp = mask   + (size_t)b * Ln;

    float h = 0.0f;
    float tot = 0.0f, msum = 0.0f;

    float tau = dp[0];
    float m   = mp[0];

    for (int t = 0; t < Ln; ++t) {
        // prefetch next step's inputs (uniform per group, L1-resident)
        const int tn = (t + 1 < Ln) ? (t + 1) : (Ln - 1);
        const float tau_n = dp[tn];
        const float m_n   = mp[tn];

        // ---- matvecs: gh = h @ w_hh^T (3 gates), pre = tau*w1t + h @ w1_h^T ----
        float hr = bhhr, hz = bhhz, hn = bhhn;
        float pre = fmaf(tau, w1t, b1i);
#pragma unroll
        for (int j = 0; j < 32; ++j) {
            const float hj = __shfl(h, j, 32);
            hr  = fmaf(whr[j], hj, hr);
            hz  = fmaf(whz[j], hj, hz);
            hn  = fmaf(whn[j], hj, hn);
            pre = fmaf(w1h[j], hj, pre);
        }

        // ---- intensity / log-likelihood (uses pre-update h) ----
        const float a  = tanhf_(pre);
        float v1 = a * w2i;                    // -> raw = sum(v1) + b2
        float v2 = fmaf(-a * a, ci, ci);       // (1-a^2)*w1t*w2 -> sum
#pragma unroll
        for (int d = 1; d < 32; d <<= 1) {
            v1 += __shfl_xor(v1, d, 32);
            v2 += __shfl_xor(v2, d, 32);
        }
        const float raw  = v1 + b2v;
        const float phi  = softplusf_(raw);
        const float dphi = sigmoidf_(raw) * v2;
        const float lam  = softplusf_(dphi) + EPSf;
        tot = fmaf(__logf(lam) - phi, m, tot);
        msum += m;

        // ---- GRU update ----
        const float r  = sigmoidf_(fmaf(tau, wihr, bihr) + hr);
        const float z  = sigmoidf_(fmaf(tau, wihz, bihz) + hz);
        const float n  = tanhf_(fmaf(r, hn, fmaf(tau, wihn, bihn)));
        const float nh = fmaf(1.0f - z, n, z * h);
        h = fmaf(m, nh - h, h);                // m*new_h + (1-m)*h

        tau = tau_n;
        m   = m_n;
    }

    // ---- block reduction: one value per 32-lane group ----
    __shared__ float s_tot[8], s_m[8];
    if (i == 0) { s_tot[grp] = tot; s_m[grp] = msum; }
    __syncthreads();
    if (tid == 0) {
        float T = 0.0f, M = 0.0f;
#pragma unroll
        for (int g = 0; g < 8; ++g) { T += s_tot[g]; M += s_m[g]; }
        partials[blockIdx.x] = T;
        partials[gridDim.x + blockIdx.x] = M;
    }
}

__global__ __launch_bounds__(256)
void tpp_final(const float* __restrict__ partials, int nparts,
               float* __restrict__ out)
{
    const int tid = threadIdx.x;
    double T = 0.0, M = 0.0;
    for (int k = tid; k < nparts; k += 256) {
        T += (double)partials[k];
        M += (double)partials[nparts + k];
    }
#pragma unroll
    for (int d = 1; d < 64; d <<= 1) {
        T += __shfl_xor(T, d, 64);
        M += __shfl_xor(M, d, 64);
    }
    __shared__ double sT[4], sM[4];
    const int w = tid >> 6;
    if ((tid & 63) == 0) { sT[w] = T; sM[w] = M; }
    __syncthreads();
    if (tid == 0) {
        const double t2 = sT[0] + sT[1] + sT[2] + sT[3];
        const double m2 = sM[0] + sM[1] + sM[2] + sM[3];
        out[0] = (float)(t2 / (m2 + (double)EPSf));
    }
}

extern "C" void kernel_launch(void* const* d_in, const int* in_sizes, int n_in,
                              void* d_out, int out_size, void* d_ws, size_t ws_size,
                              hipStream_t stream) {
    const float* deltas = (const float*)d_in[0];
    const float* mask   = (const float*)d_in[1];
    const float* w_ih   = (const float*)d_in[2];
    const float* w_hh   = (const float*)d_in[3];
    const float* b_ih   = (const float*)d_in[4];
    const float* b_hh   = (const float*)d_in[5];
    const float* w1     = (const float*)d_in[6];
    const float* b1     = (const float*)d_in[7];
    const float* w2     = (const float*)d_in[8];
    const float* b2     = (const float*)d_in[9];
    float* out = (float*)d_out;
    float* partials = (float*)d_ws;     // needs 2 * 512 * 4 B = 4 KiB

    const int nblocks = Bn / 8;         // 512
    tpp_main<<<nblocks, 256, 0, stream>>>(deltas, mask, w_ih, w_hh, b_ih, b_hh,
                                          w1, b1, w2, b2, partials);
    tpp_final<<<1, 256, 0, stream>>>(partials, nblocks, out);
}

// Round 2
// 480.674 us; speedup vs baseline: 1.3087x; 1.3087x over previous
//
#include <hip/hip_runtime.h>
#include <math.h>

// NeuralTPP: B=4096 sequences, L=512 steps, H=HH=32.
// Lane i of each 32-lane group owns hidden unit i; 2 batch elems per wave64.
// Weights register-resident (forced via __launch_bounds__(256,2) -> 256 VGPR cap;
// grid only supplies 2 waves/SIMD so this costs no occupancy).
// h broadcast via single-instruction ds_swizzle (BitMode, imm offset).
// LL transcendentals (softplus/log/sigmoid of per-elem scalars) deferred to a
// phase-2 pass over an LDS buffer so all 256 lanes do useful work on them.

constexpr int Bn = 4096;
constexpr int Ln = 512;
constexpr int Hn = 32;
constexpr float EPSf = 1e-8f;

__device__ __forceinline__ float sigmoidf_(float x) {
    return __fdividef(1.0f, 1.0f + __expf(-x));
}
__device__ __forceinline__ float tanhf_(float x) {
    x = fminf(x, 15.0f);
    const float e = __expf(2.0f * x);
    return __fdividef(e - 1.0f, e + 1.0f);
}
__device__ __forceinline__ float softplusf_(float x) {
    return fmaxf(x, 0.0f) + __logf(1.0f + __expf(-fabsf(x)));
}

template <int IMM>
__device__ __forceinline__ float swz(float v) {
    return __int_as_float(__builtin_amdgcn_ds_swizzle(__float_as_int(v), IMM));
}

__global__ __launch_bounds__(256, 2)
void tpp_main(const float* __restrict__ deltas,
              const float* __restrict__ mask,
              const float* __restrict__ w_ih,
              const float* __restrict__ w_hh,
              const float* __restrict__ b_ih,
              const float* __restrict__ b_hh,
              const float* __restrict__ w1,
              const float* __restrict__ b1,
              const float* __restrict__ w2,
              const float* __restrict__ b2,
              float* __restrict__ partials)   // [2 * gridDim.x]
{
    const int tid = threadIdx.x;
    const int grp = tid >> 5;            // 0..7
    const int i   = tid & 31;            // hidden unit
    const int b   = blockIdx.x * 8 + grp;

    __shared__ float buf[8 * Ln * 2];    // [grp][t][{raw,v2}] = 32 KiB

    // ---- weights -> registers ----
    float whr[32], whz[32], whn[32], w1h[32];
    const float* pr = w_hh + (size_t)i * Hn;
    const float* pz = w_hh + (size_t)(Hn + i) * Hn;
    const float* pn = w_hh + (size_t)(2 * Hn + i) * Hn;
    const float* p1 = w1 + (size_t)i * (Hn + 1);
#pragma unroll
    for (int j = 0; j < 32; ++j) {
        whr[j] = pr[j];
        whz[j] = pz[j];
        whn[j] = pn[j];
        w1h[j] = p1[1 + j];
    }
    const float wihr = w_ih[i], wihz = w_ih[Hn + i], wihn = w_ih[2 * Hn + i];
    const float bihn = b_ih[2 * Hn + i];
    const float br = b_ih[i] + b_hh[i];            // merged r biases
    const float bz = b_ih[Hn + i] + b_hh[Hn + i];  // merged z biases
    const float bhn = b_hh[2 * Hn + i];            // n-gate hh bias (inside r*)
    const float w1t = p1[0];
    const float b1i = b1[i];
    const float w2i = w2[i];
    const float ci  = w1t * w2i;
    const float b2v = b2[0];

    const float* dp = deltas + (size_t)b * Ln;
    const float* mp = mask   + (size_t)b * Ln;

    float h = 0.0f;
    float tau = dp[0];
    float m   = mp[0];

    for (int t = 0; t < Ln; ++t) {
        const int tn = (t + 1 < Ln) ? (t + 1) : (Ln - 1);
        const float tau_n = dp[tn];
        const float m_n   = mp[tn];

        float hr = br, hz = bz, hn = bhn;
        float pre = fmaf(tau, w1t, b1i);

        // h broadcast: one ds_swizzle per j (BitMode and=0, or=j -> lane j of group)
#define BCJ(J) { const float hj = swz<((J) << 5)>(h);            \
                 hr  = fmaf(whr[J], hj, hr);                     \
                 hz  = fmaf(whz[J], hj, hz);                     \
                 hn  = fmaf(whn[J], hj, hn);                     \
                 pre = fmaf(w1h[J], hj, pre); }
        BCJ(0)  BCJ(1)  BCJ(2)  BCJ(3)  BCJ(4)  BCJ(5)  BCJ(6)  BCJ(7)
        BCJ(8)  BCJ(9)  BCJ(10) BCJ(11) BCJ(12) BCJ(13) BCJ(14) BCJ(15)
        BCJ(16) BCJ(17) BCJ(18) BCJ(19) BCJ(20) BCJ(21) BCJ(22) BCJ(23)
        BCJ(24) BCJ(25) BCJ(26) BCJ(27) BCJ(28) BCJ(29) BCJ(30) BCJ(31)
#undef BCJ

        // ---- intensity scalars (reduced, stored; trans deferred to phase 2) ----
        const float a  = tanhf_(pre);
        float v1 = a * w2i;
        float v2 = fmaf(a * a, -ci, ci);       // (1-a^2)*w1t*w2
        // butterfly over 32 lanes: ds_swizzle xor (and=0x1f, xor=d)
#define RED(D) { v1 += swz<(((D) << 10) | 0x1f)>(v1); \
                 v2 += swz<(((D) << 10) | 0x1f)>(v2); }
        RED(1) RED(2) RED(4) RED(8) RED(16)
#undef RED
        const float raw = v1 + b2v;
        if (i < 2) buf[(grp << 10) + (t << 1) + i] = (i == 0) ? raw : v2;

        // ---- GRU update ----
        const float r  = sigmoidf_(fmaf(tau, wihr, hr));
        const float z  = sigmoidf_(fmaf(tau, wihz, hz));
        const float n  = tanhf_(fmaf(r, hn, fmaf(tau, wihn, bihn)));
        const float nh = fmaf(1.0f - z, n, z * h);
        h = fmaf(m, nh - h, h);

        tau = tau_n;
        m   = m_n;
    }

    __syncthreads();

    // ---- phase 2: LL transcendentals, all 256 lanes useful ----
    const float* mblk = mask + (size_t)blockIdx.x * 8 * Ln;
    float T = 0.0f, M = 0.0f;
#pragma unroll
    for (int k = 0; k < 16; ++k) {
        const int idx = (k << 8) + tid;            // 0..4095 over [grp][t]
        const float raw = buf[idx * 2];
        const float v2  = buf[idx * 2 + 1];
        const float mm  = mblk[idx];               // [g][t] flat == idx
        const float phi  = softplusf_(raw);
        const float dphi = sigmoidf_(raw) * v2;
        const float lam  = softplusf_(dphi) + EPSf;
        T = fmaf(__logf(lam) - phi, mm, T);
        M += mm;
    }
#pragma unroll
    for (int d = 1; d < 64; d <<= 1) {
        T += __shfl_xor(T, d, 64);
        M += __shfl_xor(M, d, 64);
    }
    __shared__ float sT[4], sM[4];
    const int w = tid >> 6;
    if ((tid & 63) == 0) { sT[w] = T; sM[w] = M; }
    __syncthreads();
    if (tid == 0) {
        partials[blockIdx.x]             = sT[0] + sT[1] + sT[2] + sT[3];
        partials[gridDim.x + blockIdx.x] = sM[0] + sM[1] + sM[2] + sM[3];
    }
}

__global__ __launch_bounds__(256)
void tpp_final(const float* __restrict__ partials, int nparts,
               float* __restrict__ out)
{
    const int tid = threadIdx.x;
    double T = 0.0, M = 0.0;
    for (int k = tid; k < nparts; k += 256) {
        T += (double)partials[k];
        M += (double)partials[nparts + k];
    }
#pragma unroll
    for (int d = 1; d < 64; d <<= 1) {
        T += __shfl_xor(T, d, 64);
        M += __shfl_xor(M, d, 64);
    }
    __shared__ double sT[4], sM[4];
    const int w = tid >> 6;
    if ((tid & 63) == 0) { sT[w] = T; sM[w] = M; }
    __syncthreads();
    if (tid == 0) {
        const double t2 = sT[0] + sT[1] + sT[2] + sT[3];
        const double m2 = sM[0] + sM[1] + sM[2] + sM[3];
        out[0] = (float)(t2 / (m2 + (double)EPSf));
    }
}

extern "C" void kernel_launch(void* const* d_in, const int* in_sizes, int n_in,
                              void* d_out, int out_size, void* d_ws, size_t ws_size,
                              hipStream_t stream) {
    const float* deltas = (const float*)d_in[0];
    const float* mask   = (const float*)d_in[1];
    const float* w_ih   = (const float*)d_in[2];
    const float* w_hh   = (const float*)d_in[3];
    const float* b_ih   = (const float*)d_in[4];
    const float* b_hh   = (const float*)d_in[5];
    const float* w1     = (const float*)d_in[6];
    const float* b1     = (const float*)d_in[7];
    const float* w2     = (const float*)d_in[8];
    const float* b2     = (const float*)d_in[9];
    float* out = (float*)d_out;
    float* partials = (float*)d_ws;     // 2 * 512 * 4 B = 4 KiB

    const int nblocks = Bn / 8;         // 512
    tpp_main<<<nblocks, 256, 0, stream>>>(deltas, mask, w_ih, w_hh, b_ih, b_hh,
                                          w1, b1, w2, b2, partials);
    tpp_final<<<1, 256, 0, stream>>>(partials, nblocks, out);
}